// Round 4
// baseline (739.811 us; speedup 1.0000x reference)
//
#include <hip/hip_runtime.h>
#include <hip/hip_bf16.h>
#include <stdint.h>

#define LVLS 16
#define TSZ  524288          // hash table size per level (2^19)
#define TMASK 0x7FFFFu
#define NPTS 524288
#define P1 2654435761u
#define P2 805459861u
#define P3 3674653429u

// floor(16 * 1.5^l) — constexpr so the unrolled level loop folds them
constexpr float RESC[16] = {
    16.f, 24.f, 36.f, 54.f, 81.f, 121.f, 182.f, 273.f,
    410.f, 615.f, 922.f, 1383.f, 2075.f, 3113.f, 4670.f, 7006.f};
__constant__ float RES_TAB[16] = {
    16.f, 24.f, 36.f, 54.f, 81.f, 121.f, 182.f, 273.f,
    410.f, 615.f, 922.f, 1383.f, 2075.f, 3113.f, 4670.f, 7006.f};

using f16x8 = __attribute__((ext_vector_type(8))) _Float16;
using f32x4 = __attribute__((ext_vector_type(4))) float;

union PackF16 { uint32_t u; _Float16 h[2]; };

constexpr int PS = 72;    // scratch pitch (64 cols + 8 pad)
constexpr int PF = 136;   // feature pitch (128 cols + 8 pad)

// ---------------------------------------------------------------------------
// Kernel W: swizzle weights (fp32 [K][N] row-major) into f16 B-fragment layout
// for mfma_f32_16x16x32_f16 (verified r1-r3):
//   dst[((ct*KC+kc)*64+lane)*8+j] = W[kc*32+(lane>>4)*8+j][ct*16+(lane&15)]
// ---------------------------------------------------------------------------
struct WPtrs { const float* p[11]; };

__global__ void k_weights(WPtrs wp, _Float16* __restrict__ dst) {
    int id = blockIdx.x * 256 + threadIdx.x;
    if (id >= 69632) return;
    const int OFF[16] = {0,2048,6144,10240,14336,18432,20480,24576,28672,
                         32768,36864,45056,49152,57344,65536,69632};
    const int KK[15]  = {32,64,64,64,64,32,64,64,64,64,128,64,64,128,64};
    const int NN[15]  = {64,64,64,64,64,64,64,64,64,64,64,64,128,64,64};
    const int PSEL[15]= {0,1,1,1,2,3,4,4,4,5,6,7,8,9,10};
    const int POFF[15]= {0,0,4096,8192,0,0,0,4096,8192,0,0,0,0,0,0};
    int m = 0;
    while (id >= OFF[m+1]) m++;
    int local = id - OFF[m];
    int j    = local & 7;
    int lane = (local >> 3) & 63;
    int blk  = local >> 9;
    int KC   = KK[m] >> 5;
    int ct   = blk / KC;
    int kc   = blk - ct * KC;
    int k    = kc*32 + ((lane>>4)<<3) + j;
    int n    = ct*16 + (lane & 15);
    const float* src = wp.p[PSEL[m]] + POFF[m];
    dst[id] = (_Float16)src[k * NN[m] + n];
}

// ---------------------------------------------------------------------------
// Kernel T: combined f16 table. Tc[l][i] = { static(i), t-blended dynamic }:
//   dynamic = (1-ft)*td[l][i^h0] + ft*td[l][i^h1]  (t-corner hashes baked in)
// ---------------------------------------------------------------------------
__global__ void k_tables(const float* __restrict__ ts, const float* __restrict__ td,
                         const float* __restrict__ tptr, uint2* __restrict__ Tc) {
    int id = blockIdx.x * 256 + threadIdx.x;   // 0 .. LVLS*TSZ-1
    int l = id >> 19, i = id & TMASK;
    float2 sv = ((const float2*)ts)[id];
    float res = RES_TAB[l];
    float tv  = tptr[0];
    float pt  = tv * res;
    float fpt = floorf(pt);
    float ft  = pt - fpt;
    uint32_t ut = (uint32_t)(int)fpt;
    uint32_t h0 = (ut * P3) & TMASK;
    uint32_t h1 = ((ut + 1u) * P3) & TMASK;
    const float2* tdl = (const float2*)td + (size_t)l * TSZ;
    float2 a = tdl[i ^ h0];
    float2 b = tdl[i ^ h1];
    PackF16 o0, o1;
    o0.h[0] = (_Float16)sv.x; o0.h[1] = (_Float16)sv.y;
    o1.h[0] = (_Float16)((1.f - ft) * a.x + ft * b.x);
    o1.h[1] = (_Float16)((1.f - ft) * a.y + ft * b.y);
    Tc[id] = make_uint2(o0.u, o1.u);
}

// ---------------------------------------------------------------------------
// Kernel E: encode, LOCKSTEP level sweep across the whole machine. One point
// per thread; x read once into regs; enc accumulated in regs; one 4 MiB level
// slice live device-wide at a time (replicated per-XCD L2). Output layout is
// [point][level] (64 B contiguous per point per chain) for coalesced stores
// here and single-b128 A-fragment loads in k_mlp.
// ---------------------------------------------------------------------------
__launch_bounds__(256)
__global__ void k_encode(const float* __restrict__ x,
                         const uint2* __restrict__ Tc,
                         uint32_t* __restrict__ EncS, uint32_t* __restrict__ EncD) {
    int p = blockIdx.x * 256 + threadIdx.x;
    float x0 = x[p*3+0], x1 = x[p*3+1], x2 = x[p*3+2];
    uint32_t outS[16], outD[16];
#pragma unroll
    for (int l = 0; l < LVLS; l++) {
        const float res = RESC[l];
        const uint2* tcl = Tc + (size_t)l * TSZ;
        float px = x0*res, py = x1*res, pz = x2*res;
        float fx = floorf(px), fy = floorf(py), fz = floorf(pz);
        float wx = px-fx, wy = py-fy, wz = pz-fz;
        uint32_t ux = (uint32_t)(int)fx, uy = (uint32_t)(int)fy, uz = (uint32_t)(int)fz;
        uint32_t hx[2] = {ux, ux + 1u};
        uint32_t hy[2] = {uy * P1, (uy + 1u) * P1};
        uint32_t hz[2] = {uz * P2, (uz + 1u) * P2};
        uint2 v[8];
#pragma unroll
        for (int c = 0; c < 8; c++) {
            uint32_t idx = (hx[c&1] ^ hy[(c>>1)&1] ^ hz[c>>2]) & TMASK;
            v[c] = tcl[idx];
        }
        float wxa[2] = {1.f-wx, wx}, wya[2] = {1.f-wy, wy}, wza[2] = {1.f-wz, wz};
        float sA0 = 0.f, sA1 = 0.f, sD0 = 0.f, sD1 = 0.f;
#pragma unroll
        for (int c = 0; c < 8; c++) {
            float w = wxa[c&1] * wya[(c>>1)&1] * wza[c>>2];
            PackF16 s, d; s.u = v[c].x; d.u = v[c].y;
            sA0 += w * (float)s.h[0]; sA1 += w * (float)s.h[1];
            sD0 += w * (float)d.h[0]; sD1 += w * (float)d.h[1];
        }
        PackF16 o;
        o.h[0] = (_Float16)sA0; o.h[1] = (_Float16)sA1; outS[l] = o.u;
        o.h[0] = (_Float16)sD0; o.h[1] = (_Float16)sD1; outD[l] = o.u;
    }
    uint4* es = (uint4*)(EncS + (size_t)p * 16);
    uint4* ed = (uint4*)(EncD + (size_t)p * 16);
#pragma unroll
    for (int i = 0; i < 4; i++) {
        es[i] = make_uint4(outS[4*i], outS[4*i+1], outS[4*i+2], outS[4*i+3]);
        ed[i] = make_uint4(outD[4*i], outD[4*i+1], outD[4*i+2], outD[4*i+3]);
    }
}

// ---------------------------------------------------------------------------
// Kernel M: layer-synchronized MLP. Block = 128 points, wave = 32 points
// (2 row-tiles, B-frag reg-reuse x2). Per stage, the layer's weight frags are
// staged into a 16 KB LDS buffer shared by all 4 waves (kills the per-MFMA
// global weight stream). Activation scratch: S (64 cols), F (128 cols, skip
// features; dynamic chain scratch overlaid in F cols 64..127 — r3-verified).
// Fragment maps: A[m=lane&15][k=quad*8+j], D row=quad*4+i, col=lane&15.
// ---------------------------------------------------------------------------
__device__ __forceinline__ void wait_lds() {
    asm volatile("s_waitcnt lgkmcnt(0)" ::: "memory");
}

// aX[rt][kc] regs -> MFMA with B from LDS Wt -> write f16 D to dst (pitch)
template<int KC, bool RELU>
__device__ __forceinline__ void mm2(const f16x8 a[2][4], const f16x8* __restrict__ B,
                                    _Float16* dst, int pitch,
                                    int rbase, int m, int quad, int lane) {
#pragma unroll
    for (int ct = 0; ct < 4; ct++) {
        f32x4 acc0 = {0.f,0.f,0.f,0.f}, acc1 = {0.f,0.f,0.f,0.f};
#pragma unroll
        for (int kc = 0; kc < KC; kc++) {
            f16x8 b = B[(ct*KC+kc)*64 + lane];
            acc0 = __builtin_amdgcn_mfma_f32_16x16x32_f16(a[0][kc], b, acc0, 0, 0, 0);
            acc1 = __builtin_amdgcn_mfma_f32_16x16x32_f16(a[1][kc], b, acc1, 0, 0, 0);
        }
#pragma unroll
        for (int i = 0; i < 4; i++) {
            float v0 = acc0[i], v1 = acc1[i];
            if (RELU) { v0 = fmaxf(v0, 0.f); v1 = fmaxf(v1, 0.f); }
            dst[(rbase + 0*16 + quad*4+i)*pitch + ct*16 + m] = (_Float16)v0;
            dst[(rbase + 1*16 + quad*4+i)*pitch + ct*16 + m] = (_Float16)v1;
        }
    }
}

// linear-out: write D to dst AND keep packed f16 copies (skip connection)
template<int KC>
__device__ __forceinline__ void mm2_keep(const f16x8 a[2][4], const f16x8* __restrict__ B,
                                         _Float16* dst, int pitch, PackF16 P[2][8],
                                         int rbase, int m, int quad, int lane) {
#pragma unroll
    for (int ct = 0; ct < 4; ct++) {
        f32x4 acc0 = {0.f,0.f,0.f,0.f}, acc1 = {0.f,0.f,0.f,0.f};
#pragma unroll
        for (int kc = 0; kc < KC; kc++) {
            f16x8 b = B[(ct*KC+kc)*64 + lane];
            acc0 = __builtin_amdgcn_mfma_f32_16x16x32_f16(a[0][kc], b, acc0, 0, 0, 0);
            acc1 = __builtin_amdgcn_mfma_f32_16x16x32_f16(a[1][kc], b, acc1, 0, 0, 0);
        }
#pragma unroll
        for (int ih = 0; ih < 2; ih++) {
            PackF16 p0, p1;
            p0.h[0] = (_Float16)acc0[ih*2+0]; p0.h[1] = (_Float16)acc0[ih*2+1];
            p1.h[0] = (_Float16)acc1[ih*2+0]; p1.h[1] = (_Float16)acc1[ih*2+1];
            P[0][ct*2+ih] = p0; P[1][ct*2+ih] = p1;
            dst[(rbase + 0*16 + quad*4+ih*2+0)*pitch + ct*16 + m] = p0.h[0];
            dst[(rbase + 0*16 + quad*4+ih*2+1)*pitch + ct*16 + m] = p0.h[1];
            dst[(rbase + 1*16 + quad*4+ih*2+0)*pitch + ct*16 + m] = p1.h[0];
            dst[(rbase + 1*16 + quad*4+ih*2+1)*pitch + ct*16 + m] = p1.h[1];
        }
    }
}

template<int KC>
__device__ __forceinline__ void read_a(const _Float16* buf, int pitch,
                                       f16x8 a[2][4], int rbase, int m, int quad) {
#pragma unroll
    for (int rt = 0; rt < 2; rt++)
#pragma unroll
        for (int kc = 0; kc < KC; kc++)
            a[rt][kc] = *(const f16x8*)(buf + (rbase + rt*16 + m)*pitch + kc*32 + quad*8);
}

__launch_bounds__(256, 4)
__global__ void k_mlp(const uint32_t* __restrict__ EncS, const uint32_t* __restrict__ EncD,
                      const _Float16* __restrict__ Wfrag, const float* __restrict__ alphap,
                      const float* __restrict__ w2out, float* __restrict__ out) {
    __shared__ f16x8    Wt[1024];          // 16 KB staged weight frags
    __shared__ _Float16 S [128*PS];        // 18.4 KB scratch (64 cols)
    __shared__ _Float16 F [128*PF];        // 34.8 KB skip features (128 cols)
    int tid  = threadIdx.x;
    int wave = tid >> 6, lane = tid & 63;
    int m = lane & 15, quad = lane >> 4;
    int rbase = wave * 32;
    int pbase = blockIdx.x * 128 + rbase;
    const f16x8* Wg = (const f16x8*)Wfrag;
    float alpha = alphap[0];

    f16x8 aS[2][4], aD[2][4];
    PackF16 sP[2][8], dP[2][8];

    // enc inputs: one b128 per rt per chain ([point][level] layout)
#pragma unroll
    for (int rt = 0; rt < 2; rt++) {
        aS[rt][0] = *(const f16x8*)(EncS + (size_t)(pbase + rt*16 + m)*16 + quad*4);
        aD[rt][0] = *(const f16x8*)(EncD + (size_t)(pbase + rt*16 + m)*16 + quad*4);
    }

    // stage s: copy [g0,g0+c0) -> Wt[0..c0), [g1,g1+c1) -> Wt[c0..c0+c1)
#define STAGE2(g0,c0,g1,c1)                                              \
    __syncthreads();                                                     \
    for (int i = tid; i < (c0); i += 256) Wt[i] = Wg[(g0)+i];            \
    for (int i = tid; i < (c1); i += 256) Wt[(c0)+i] = Wg[(g1)+i];       \
    __syncthreads();
#define STAGE1(g0,c0)                                                    \
    __syncthreads();                                                     \
    for (int i = tid; i < (c0); i += 256) Wt[i] = Wg[(g0)+i];            \
    __syncthreads();

    _Float16* D = F + 64;   // dynamic chain scratch = F cols 64..127

    // ---- encoder chains (static scratch=S, dynamic scratch=D) ----
    STAGE2(0, 256, 2304, 256)
    mm2<1, true>(aS, Wt,       S, PS, rbase, m, quad, lane);
    mm2<1, true>(aD, Wt + 256, D, PF, rbase, m, quad, lane);
    wait_lds();
    read_a<2>(S, PS, aS, rbase, m, quad);
    read_a<2>(D, PF, aD, rbase, m, quad);
    STAGE2(256, 512, 2560, 512)
    mm2<2, true>(aS, Wt,       S, PS, rbase, m, quad, lane);
    mm2<2, true>(aD, Wt + 512, D, PF, rbase, m, quad, lane);
    wait_lds();
    read_a<2>(S, PS, aS, rbase, m, quad);
    read_a<2>(D, PF, aD, rbase, m, quad);
    STAGE2(768, 512, 3072, 512)
    mm2<2, true>(aS, Wt,       S, PS, rbase, m, quad, lane);
    mm2<2, true>(aD, Wt + 512, D, PF, rbase, m, quad, lane);
    wait_lds();
    read_a<2>(S, PS, aS, rbase, m, quad);
    read_a<2>(D, PF, aD, rbase, m, quad);
    STAGE2(1280, 512, 3584, 512)
    mm2<2, true>(aS, Wt,       S, PS, rbase, m, quad, lane);
    mm2<2, true>(aD, Wt + 512, D, PF, rbase, m, quad, lane);
    wait_lds();
    read_a<2>(S, PS, aS, rbase, m, quad);
    read_a<2>(D, PF, aD, rbase, m, quad);
    STAGE2(1792, 512, 4096, 512)
    mm2_keep<2>(aS, Wt,       F, PF, sP, rbase, m, quad, lane);  // F cols 0..63
    mm2_keep<2>(aD, Wt + 512, D, PF, dP, rbase, m, quad, lane);  // F cols 64..127
    wait_lds();
    // ---- mlp1: 128->64 relu, 64->64 relu ----
    read_a<4>(F, PF, aS, rbase, m, quad);
    STAGE1(4608, 1024)
    mm2<4, true>(aS, Wt, S, PS, rbase, m, quad, lane);
    wait_lds();
    read_a<2>(S, PS, aS, rbase, m, quad);
    STAGE1(5632, 512)
    mm2<2, true>(aS, Wt, S, PS, rbase, m, quad, lane);
    wait_lds();
    read_a<2>(S, PS, aS, rbase, m, quad);
    // ---- out1 (64->128) fused with skip blend, into F ----
    STAGE1(6144, 1024)
#pragma unroll
    for (int ct = 0; ct < 8; ct++) {
        f32x4 acc0 = {0.f,0.f,0.f,0.f}, acc1 = {0.f,0.f,0.f,0.f};
#pragma unroll
        for (int kc = 0; kc < 2; kc++) {
            f16x8 b = Wt[(ct*2+kc)*64 + lane];
            acc0 = __builtin_amdgcn_mfma_f32_16x16x32_f16(aS[0][kc], b, acc0, 0, 0, 0);
            acc1 = __builtin_amdgcn_mfma_f32_16x16x32_f16(aS[1][kc], b, acc1, 0, 0, 0);
        }
#pragma unroll
        for (int i = 0; i < 4; i++) {
            float f0 = (ct < 4) ? (float)sP[0][ct*2 + (i>>1)].h[i&1]
                                : (float)dP[0][(ct-4)*2 + (i>>1)].h[i&1];
            float f1 = (ct < 4) ? (float)sP[1][ct*2 + (i>>1)].h[i&1]
                                : (float)dP[1][(ct-4)*2 + (i>>1)].h[i&1];
            F[(rbase + 0*16 + quad*4+i)*PF + ct*16 + m] = (_Float16)(alpha*acc0[i] + (1.f-alpha)*f0);
            F[(rbase + 1*16 + quad*4+i)*PF + ct*16 + m] = (_Float16)(alpha*acc1[i] + (1.f-alpha)*f1);
        }
    }
    wait_lds();
    // ---- mlp2: 128->64 relu, 64->64 relu, dot w2_out ----
    read_a<4>(F, PF, aS, rbase, m, quad);
    STAGE1(7168, 1024)
    mm2<4, true>(aS, Wt, S, PS, rbase, m, quad, lane);
    wait_lds();
    read_a<2>(S, PS, aS, rbase, m, quad);
    STAGE1(8192, 512)
    float rsum0[4] = {0.f,0.f,0.f,0.f}, rsum1[4] = {0.f,0.f,0.f,0.f};
#pragma unroll
    for (int ct = 0; ct < 4; ct++) {
        f32x4 acc0 = {0.f,0.f,0.f,0.f}, acc1 = {0.f,0.f,0.f,0.f};
#pragma unroll
        for (int kc = 0; kc < 2; kc++) {
            f16x8 b = Wt[(ct*2+kc)*64 + lane];
            acc0 = __builtin_amdgcn_mfma_f32_16x16x32_f16(aS[0][kc], b, acc0, 0, 0, 0);
            acc1 = __builtin_amdgcn_mfma_f32_16x16x32_f16(aS[1][kc], b, acc1, 0, 0, 0);
        }
        float wv = w2out[ct*16 + m];
#pragma unroll
        for (int i = 0; i < 4; i++) {
            rsum0[i] += fmaxf(acc0[i], 0.f) * wv;
            rsum1[i] += fmaxf(acc1[i], 0.f) * wv;
        }
    }
#pragma unroll
    for (int off = 1; off < 16; off <<= 1) {
#pragma unroll
        for (int i = 0; i < 4; i++) {
            rsum0[i] += __shfl_xor(rsum0[i], off, 64);
            rsum1[i] += __shfl_xor(rsum1[i], off, 64);
        }
    }
    if (m == 0) {
#pragma unroll
        for (int i = 0; i < 4; i++) {
            out[pbase + 0*16 + quad*4 + i] = rsum0[i];
            out[pbase + 1*16 + quad*4 + i] = rsum1[i];
        }
    }
#undef STAGE1
#undef STAGE2
}

// ---------------------------------------------------------------------------
extern "C" void kernel_launch(void* const* d_in, const int* in_sizes, int n_in,
                              void* d_out, int out_size, void* d_ws, size_t ws_size,
                              hipStream_t stream) {
    const float* x      = (const float*)d_in[0];
    const float* t      = (const float*)d_in[1];
    const float* alpha  = (const float*)d_in[2];
    const float* tab_s  = (const float*)d_in[3];
    const float* ws_in  = (const float*)d_in[4];
    const float* ws_hid = (const float*)d_in[5];
    const float* ws_out = (const float*)d_in[6];
    const float* tab_d  = (const float*)d_in[7];
    const float* wd_in  = (const float*)d_in[8];
    const float* wd_hid = (const float*)d_in[9];
    const float* wd_out = (const float*)d_in[10];
    const float* w1_in  = (const float*)d_in[11];
    const float* w1_hid = (const float*)d_in[12];
    const float* w1_out = (const float*)d_in[13];
    const float* w2_in  = (const float*)d_in[14];
    const float* w2_hid = (const float*)d_in[15];
    const float* w2_out = (const float*)d_in[16];
    float* out = (float*)d_out;

    char* ws = (char*)d_ws;
    _Float16* Wfrag = (_Float16*)ws;                       // 139264 B
    uint2*    Tc    = (uint2*)(ws + 139264);               // 64 MiB combined table
    uint32_t* EncS  = (uint32_t*)(ws + 139264 + 67108864); // 32 MiB [pt][lvl]
    uint32_t* EncD  = EncS + (size_t)LVLS * NPTS;          // 32 MiB [pt][lvl]
    size_t needed = 139264 + 67108864 + 2ull * 33554432ull;
    if (ws_size < needed) return;

    WPtrs wp;
    wp.p[0] = ws_in;  wp.p[1] = ws_hid; wp.p[2] = ws_out;
    wp.p[3] = wd_in;  wp.p[4] = wd_hid; wp.p[5] = wd_out;
    wp.p[6] = w1_in;  wp.p[7] = w1_hid; wp.p[8] = w1_out;
    wp.p[9] = w2_in;  wp.p[10] = w2_hid;

    k_weights<<<272,   256, 0, stream>>>(wp, Wfrag);
    k_tables <<<32768, 256, 0, stream>>>(tab_s, tab_d, t, Tc);
    k_encode <<<2048,  256, 0, stream>>>(x, Tc, EncS, EncD);
    k_mlp    <<<NPTS/128, 256, 0, stream>>>(EncS, EncD, Wfrag, alpha, w2_out, out);
}

// Round 5
// 655.112 us; speedup vs baseline: 1.1293x; 1.1293x over previous
//
#include <hip/hip_runtime.h>
#include <hip/hip_bf16.h>
#include <stdint.h>

#define LVLS 16
#define TSZ  524288          // hash table size per level (2^19)
#define TMASK 0x7FFFFu
#define NPTS 524288
#define P1 2654435761u
#define P2 805459861u
#define P3 3674653429u

// floor(16 * 1.5^l), hardcoded
__constant__ float RES_TAB[16] = {
    16.f, 24.f, 36.f, 54.f, 81.f, 121.f, 182.f, 273.f,
    410.f, 615.f, 922.f, 1383.f, 2075.f, 3113.f, 4670.f, 7006.f};

using f16x8 = __attribute__((ext_vector_type(8))) _Float16;
using f32x4 = __attribute__((ext_vector_type(4))) float;

union PackF16 { uint32_t u; _Float16 h[2]; };

constexpr int PS = 72;    // LDS row pitch (64 cols + 8 pad)

// ---------------------------------------------------------------------------
// Kernel W: swizzle weights (fp32 [K][N] row-major) into f16 B-fragment layout
// for mfma_f32_16x16x32_f16 (verified r1-r4):
//   dst[((ct*KC+kc)*64+lane)*8+j] = W[kc*32+(lane>>4)*8+j][ct*16+(lane&15)]
// ---------------------------------------------------------------------------
struct WPtrs { const float* p[11]; };

__global__ void k_weights(WPtrs wp, _Float16* __restrict__ dst) {
    int id = blockIdx.x * 256 + threadIdx.x;
    if (id >= 69632) return;
    const int OFF[16] = {0,2048,6144,10240,14336,18432,20480,24576,28672,
                         32768,36864,45056,49152,57344,65536,69632};
    const int KK[15]  = {32,64,64,64,64,32,64,64,64,64,128,64,64,128,64};
    const int NN[15]  = {64,64,64,64,64,64,64,64,64,64,64,64,128,64,64};
    const int PSEL[15]= {0,1,1,1,2,3,4,4,4,5,6,7,8,9,10};
    const int POFF[15]= {0,0,4096,8192,0,0,0,4096,8192,0,0,0,0,0,0};
    int m = 0;
    while (id >= OFF[m+1]) m++;
    int local = id - OFF[m];
    int j    = local & 7;
    int lane = (local >> 3) & 63;
    int blk  = local >> 9;
    int KC   = KK[m] >> 5;
    int ct   = blk / KC;
    int kc   = blk - ct * KC;
    int k    = kc*32 + ((lane>>4)<<3) + j;
    int n    = ct*16 + (lane & 15);
    const float* src = wp.p[PSEL[m]] + POFF[m];
    dst[id] = (_Float16)src[k * NN[m] + n];
}

// ---------------------------------------------------------------------------
// Kernel T: combined f16 table. Tc[l][i] = { static(i), t-blended dynamic }:
//   dynamic = (1-ft)*td[l][i^h0] + ft*td[l][i^h1]  (t-corner hashes baked in)
// ---------------------------------------------------------------------------
__global__ void k_tables(const float* __restrict__ ts, const float* __restrict__ td,
                         const float* __restrict__ tptr, uint2* __restrict__ Tc) {
    int id = blockIdx.x * 256 + threadIdx.x;   // 0 .. LVLS*TSZ-1
    int l = id >> 19, i = id & TMASK;
    float2 sv = ((const float2*)ts)[id];
    float res = RES_TAB[l];
    float tv  = tptr[0];
    float pt  = tv * res;
    float fpt = floorf(pt);
    float ft  = pt - fpt;
    uint32_t ut = (uint32_t)(int)fpt;
    uint32_t h0 = (ut * P3) & TMASK;
    uint32_t h1 = ((ut + 1u) * P3) & TMASK;
    const float2* tdl = (const float2*)td + (size_t)l * TSZ;
    float2 a = tdl[i ^ h0];
    float2 b = tdl[i ^ h1];
    PackF16 o0, o1;
    o0.h[0] = (_Float16)sv.x; o0.h[1] = (_Float16)sv.y;
    o1.h[0] = (_Float16)((1.f - ft) * a.x + ft * b.x);
    o1.h[1] = (_Float16)((1.f - ft) * a.y + ft * b.y);
    Tc[id] = make_uint2(o0.u, o1.u);
}

// ---------------------------------------------------------------------------
// Kernel E: hash-grid encode, XCD-sharded with BALANCED units.
// Hard levels 4..15 -> 24 (level, point-half) units; class c = blockIdx&7
// (XCD-pinned by round-robin dispatch) runs units 3c..3c+2 sequentially, so
// at most one 4 MiB level slice is live per XCD at a time (r2-verified
// residency). Coarse levels 0..3 (tiny, cache-resident) go to classes 0..3.
// Batch of 4 points -> 32 outstanding 8 B gathers to cover miss latency.
// Output layout [lvl][pt] (coalesced stores).
// ---------------------------------------------------------------------------
__device__ __forceinline__ void enc_batch4(const float* __restrict__ x,
                                           const uint2* __restrict__ tcl, float res,
                                           uint32_t* __restrict__ es,
                                           uint32_t* __restrict__ ed, int pb) {
    int p[4];
    uint32_t idx[4][8];
    float wxa[4][2], wya[4][2], wza[4][2];
#pragma unroll
    for (int b = 0; b < 4; b++) {
        p[b] = pb + b * 65536;
        float px = x[p[b]*3+0]*res, py = x[p[b]*3+1]*res, pz = x[p[b]*3+2]*res;
        float fx = floorf(px), fy = floorf(py), fz = floorf(pz);
        float wx = px-fx, wy = py-fy, wz = pz-fz;
        uint32_t ux = (uint32_t)(int)fx, uy = (uint32_t)(int)fy, uz = (uint32_t)(int)fz;
        uint32_t hx[2] = {ux, ux + 1u};
        uint32_t hy[2] = {uy * P1, (uy + 1u) * P1};
        uint32_t hz[2] = {uz * P2, (uz + 1u) * P2};
#pragma unroll
        for (int c = 0; c < 8; c++)
            idx[b][c] = (hx[c&1] ^ hy[(c>>1)&1] ^ hz[c>>2]) & TMASK;
        wxa[b][0] = 1.f-wx; wxa[b][1] = wx;
        wya[b][0] = 1.f-wy; wya[b][1] = wy;
        wza[b][0] = 1.f-wz; wza[b][1] = wz;
    }
    uint2 v[4][8];
#pragma unroll
    for (int b = 0; b < 4; b++)
#pragma unroll
        for (int c = 0; c < 8; c++)
            v[b][c] = tcl[idx[b][c]];
#pragma unroll
    for (int b = 0; b < 4; b++) {
        float sA0 = 0.f, sA1 = 0.f, sD0 = 0.f, sD1 = 0.f;
#pragma unroll
        for (int c = 0; c < 8; c++) {
            float w = wxa[b][c&1] * wya[b][(c>>1)&1] * wza[b][c>>2];
            PackF16 s, d; s.u = v[b][c].x; d.u = v[b][c].y;
            sA0 += w * (float)s.h[0]; sA1 += w * (float)s.h[1];
            sD0 += w * (float)d.h[0]; sD1 += w * (float)d.h[1];
        }
        PackF16 o;
        o.h[0] = (_Float16)sA0; o.h[1] = (_Float16)sA1; es[p[b]] = o.u;
        o.h[0] = (_Float16)sD0; o.h[1] = (_Float16)sD1; ed[p[b]] = o.u;
    }
}

__launch_bounds__(256)
__global__ void k_encode(const float* __restrict__ x,
                         const uint2* __restrict__ Tc,
                         uint32_t* __restrict__ EncS, uint32_t* __restrict__ EncD) {
    int tid = threadIdx.x;
    int cls = blockIdx.x & 7;
    int gt  = (blockIdx.x >> 3) * 256 + tid;   // 0..65535 within class
    // 3 hard half-units
#pragma unroll
    for (int u3 = 0; u3 < 3; u3++) {
        int u = cls * 3 + u3;
        int l = 4 + (u >> 1);
        int pb = (u & 1) * 262144 + gt;
        enc_batch4(x, Tc + (size_t)l * TSZ, RES_TAB[l],
                   EncS + (size_t)l * NPTS, EncD + (size_t)l * NPTS, pb);
    }
    // coarse levels 0..3 (cache-resident, cheap)
    if (cls < 4) {
        int l = cls;
        enc_batch4(x, Tc + (size_t)l * TSZ, RES_TAB[l],
                   EncS + (size_t)l * NPTS, EncD + (size_t)l * NPTS, gt);
        enc_batch4(x, Tc + (size_t)l * TSZ, RES_TAB[l],
                   EncS + (size_t)l * NPTS, EncD + (size_t)l * NPTS, gt + 262144);
    }
}

// ---------------------------------------------------------------------------
// Kernel M: barrier-free MLP. Wave-private 32-point tiles (rt=2 row-tiles,
// B-frag register reuse x2); B-fragments from global (L1-resident, ~140 KB
// total weights). IN-PLACE layers: within a wave every A-fragment is staged
// to registers before any D-write issues (data dep + in-order per-wave DS),
// so a 64->64 layer can read and write the SAME buffer. Per wave only two
// 32x72 f16 buffers (Fs, Fd) -> 36.9 KB/block -> 4 blocks/CU, 16 waves/CU.
// Skip features kept in regs (sP/dP, D-layout); blend writes into Fs|Fd.
// Fragment maps (verified r1): A[m=lane&15][k=quad*8+j], D row=quad*4+i,
// col=lane&15.
// ---------------------------------------------------------------------------
__device__ __forceinline__ void wait_lds() {
    asm volatile("s_waitcnt lgkmcnt(0)" ::: "memory");
}

template<int KC, bool RELU>
__device__ __forceinline__ void mm2(const f16x8 a[2][4], const f16x8* __restrict__ B,
                                    _Float16* dst, int m, int quad, int lane) {
#pragma unroll
    for (int ct = 0; ct < 4; ct++) {
        f32x4 acc0 = {0.f,0.f,0.f,0.f}, acc1 = {0.f,0.f,0.f,0.f};
#pragma unroll
        for (int kc = 0; kc < KC; kc++) {
            f16x8 b = B[(ct*KC+kc)*64 + lane];
            acc0 = __builtin_amdgcn_mfma_f32_16x16x32_f16(a[0][kc], b, acc0, 0, 0, 0);
            acc1 = __builtin_amdgcn_mfma_f32_16x16x32_f16(a[1][kc], b, acc1, 0, 0, 0);
        }
#pragma unroll
        for (int i = 0; i < 4; i++) {
            float v0 = acc0[i], v1 = acc1[i];
            if (RELU) { v0 = fmaxf(v0, 0.f); v1 = fmaxf(v1, 0.f); }
            dst[(0*16 + quad*4+i)*PS + ct*16 + m] = (_Float16)v0;
            dst[(1*16 + quad*4+i)*PS + ct*16 + m] = (_Float16)v1;
        }
    }
}

// linear-out layer: write D to dst AND keep packed f16 copy (skip connection)
template<int KC>
__device__ __forceinline__ void mm2_keep(const f16x8 a[2][4], const f16x8* __restrict__ B,
                                         _Float16* dst, PackF16 P[2][8],
                                         int m, int quad, int lane) {
#pragma unroll
    for (int ct = 0; ct < 4; ct++) {
        f32x4 acc0 = {0.f,0.f,0.f,0.f}, acc1 = {0.f,0.f,0.f,0.f};
#pragma unroll
        for (int kc = 0; kc < KC; kc++) {
            f16x8 b = B[(ct*KC+kc)*64 + lane];
            acc0 = __builtin_amdgcn_mfma_f32_16x16x32_f16(a[0][kc], b, acc0, 0, 0, 0);
            acc1 = __builtin_amdgcn_mfma_f32_16x16x32_f16(a[1][kc], b, acc1, 0, 0, 0);
        }
#pragma unroll
        for (int ih = 0; ih < 2; ih++) {
            PackF16 p0, p1;
            p0.h[0] = (_Float16)acc0[ih*2+0]; p0.h[1] = (_Float16)acc0[ih*2+1];
            p1.h[0] = (_Float16)acc1[ih*2+0]; p1.h[1] = (_Float16)acc1[ih*2+1];
            P[0][ct*2+ih] = p0; P[1][ct*2+ih] = p1;
            dst[(0*16 + quad*4+ih*2+0)*PS + ct*16 + m] = p0.h[0];
            dst[(0*16 + quad*4+ih*2+1)*PS + ct*16 + m] = p0.h[1];
            dst[(1*16 + quad*4+ih*2+0)*PS + ct*16 + m] = p1.h[0];
            dst[(1*16 + quad*4+ih*2+1)*PS + ct*16 + m] = p1.h[1];
        }
    }
}

template<int KC>
__device__ __forceinline__ void read_a(const _Float16* buf, f16x8 a[2][4], int m, int quad) {
#pragma unroll
    for (int rt = 0; rt < 2; rt++)
#pragma unroll
        for (int kc = 0; kc < KC; kc++)
            a[rt][kc] = *(const f16x8*)(buf + (rt*16 + m)*PS + kc*32 + quad*8);
}

__device__ __forceinline__ void read_a128(const _Float16* Fs, const _Float16* Fd,
                                          f16x8 a[2][4], int m, int quad) {
#pragma unroll
    for (int rt = 0; rt < 2; rt++) {
#pragma unroll
        for (int kc = 0; kc < 2; kc++) {
            a[rt][kc]   = *(const f16x8*)(Fs + (rt*16 + m)*PS + kc*32 + quad*8);
            a[rt][kc+2] = *(const f16x8*)(Fd + (rt*16 + m)*PS + kc*32 + quad*8);
        }
    }
}

__device__ __forceinline__ void load_enc(const uint32_t* __restrict__ Enc,
                                         int pbase, int m, int quad, f16x8 a[2][4]) {
#pragma unroll
    for (int rt = 0; rt < 2; rt++) {
        union { uint32_t u[4]; f16x8 v; } cv;
        int p = pbase + rt*16 + m;
#pragma unroll
        for (int j = 0; j < 4; j++)
            cv.u[j] = Enc[(size_t)(quad*4 + j) * NPTS + p];
        a[rt][0] = cv.v;
    }
}

__launch_bounds__(256, 4)
__global__ void k_mlp(const uint32_t* __restrict__ EncS, const uint32_t* __restrict__ EncD,
                      const _Float16* __restrict__ Wfrag, const float* __restrict__ alphap,
                      const float* __restrict__ w2out, float* __restrict__ out) {
    __shared__ _Float16 FsB[4][32*PS];
    __shared__ _Float16 FdB[4][32*PS];
    int tid  = threadIdx.x;
    int wave = tid >> 6, lane = tid & 63;
    int m = lane & 15, quad = lane >> 4;
    int pbase = blockIdx.x * 128 + wave * 32;
    _Float16* Fs = FsB[wave];
    _Float16* Fd = FdB[wave];
    const f16x8* W8 = (const f16x8*)Wfrag;
    float alpha = alphap[0];

    f16x8 a[2][4];
    PackF16 sP[2][8], dP[2][8];

    // ---- static encoder chain, in-place in Fs ----
    load_enc(EncS, pbase, m, quad, a);
    mm2<1, true>(a, W8 + 0,    Fs, m, quad, lane); wait_lds();
    read_a<2>(Fs, a, m, quad);
    mm2<2, true>(a, W8 + 256,  Fs, m, quad, lane); wait_lds();
    read_a<2>(Fs, a, m, quad);
    mm2<2, true>(a, W8 + 768,  Fs, m, quad, lane); wait_lds();
    read_a<2>(Fs, a, m, quad);
    mm2<2, true>(a, W8 + 1280, Fs, m, quad, lane); wait_lds();
    read_a<2>(Fs, a, m, quad);
    mm2_keep<2>(a, W8 + 1792, Fs, sP, m, quad, lane);
    // ---- dynamic encoder chain, in-place in Fd ----
    load_enc(EncD, pbase, m, quad, a);
    mm2<1, true>(a, W8 + 2304, Fd, m, quad, lane); wait_lds();
    read_a<2>(Fd, a, m, quad);
    mm2<2, true>(a, W8 + 2560, Fd, m, quad, lane); wait_lds();
    read_a<2>(Fd, a, m, quad);
    mm2<2, true>(a, W8 + 3072, Fd, m, quad, lane); wait_lds();
    read_a<2>(Fd, a, m, quad);
    mm2<2, true>(a, W8 + 3584, Fd, m, quad, lane); wait_lds();
    read_a<2>(Fd, a, m, quad);
    mm2_keep<2>(a, W8 + 4096, Fd, dP, m, quad, lane); wait_lds();
    // ---- mlp1: 128->64 relu (reads Fs|Fd, writes Fs), 64->64 relu ----
    read_a128(Fs, Fd, a, m, quad);
    mm2<4, true>(a, W8 + 4608, Fs, m, quad, lane); wait_lds();
    read_a<2>(Fs, a, m, quad);
    mm2<2, true>(a, W8 + 5632, Fs, m, quad, lane); wait_lds();
    read_a<2>(Fs, a, m, quad);
    // ---- out1 (64->128) fused with skip blend -> Fs (cols 0..63) | Fd ----
#pragma unroll
    for (int ct = 0; ct < 8; ct++) {
        f32x4 acc0 = {0.f,0.f,0.f,0.f}, acc1 = {0.f,0.f,0.f,0.f};
#pragma unroll
        for (int kc = 0; kc < 2; kc++) {
            f16x8 b = W8[6144 + (ct*2+kc)*64 + lane];
            acc0 = __builtin_amdgcn_mfma_f32_16x16x32_f16(a[0][kc], b, acc0, 0, 0, 0);
            acc1 = __builtin_amdgcn_mfma_f32_16x16x32_f16(a[1][kc], b, acc1, 0, 0, 0);
        }
        _Float16* tgt = (ct < 4) ? Fs : Fd;
        int col = (ct & 3) * 16 + m;
#pragma unroll
        for (int i = 0; i < 4; i++) {
            float f0 = (ct < 4) ? (float)sP[0][ct*2 + (i>>1)].h[i&1]
                                : (float)dP[0][(ct-4)*2 + (i>>1)].h[i&1];
            float f1 = (ct < 4) ? (float)sP[1][ct*2 + (i>>1)].h[i&1]
                                : (float)dP[1][(ct-4)*2 + (i>>1)].h[i&1];
            tgt[(0*16 + quad*4+i)*PS + col] = (_Float16)(alpha*acc0[i] + (1.f-alpha)*f0);
            tgt[(1*16 + quad*4+i)*PS + col] = (_Float16)(alpha*acc1[i] + (1.f-alpha)*f1);
        }
    }
    wait_lds();
    // ---- mlp2: 128->64 relu (reads Fs|Fd, writes Fs), 64->64 relu, dot ----
    read_a128(Fs, Fd, a, m, quad);
    mm2<4, true>(a, W8 + 7168, Fs, m, quad, lane); wait_lds();
    read_a<2>(Fs, a, m, quad);
    float rsum0[4] = {0.f,0.f,0.f,0.f}, rsum1[4] = {0.f,0.f,0.f,0.f};
#pragma unroll
    for (int ct = 0; ct < 4; ct++) {
        f32x4 acc0 = {0.f,0.f,0.f,0.f}, acc1 = {0.f,0.f,0.f,0.f};
#pragma unroll
        for (int kc = 0; kc < 2; kc++) {
            f16x8 b = W8[8192 + (ct*2+kc)*64 + lane];
            acc0 = __builtin_amdgcn_mfma_f32_16x16x32_f16(a[0][kc], b, acc0, 0, 0, 0);
            acc1 = __builtin_amdgcn_mfma_f32_16x16x32_f16(a[1][kc], b, acc1, 0, 0, 0);
        }
        float wv = w2out[ct*16 + m];
#pragma unroll
        for (int i = 0; i < 4; i++) {
            rsum0[i] += fmaxf(acc0[i], 0.f) * wv;
            rsum1[i] += fmaxf(acc1[i], 0.f) * wv;
        }
    }
#pragma unroll
    for (int off = 1; off < 16; off <<= 1) {
#pragma unroll
        for (int i = 0; i < 4; i++) {
            rsum0[i] += __shfl_xor(rsum0[i], off, 64);
            rsum1[i] += __shfl_xor(rsum1[i], off, 64);
        }
    }
    if (m == 0) {
#pragma unroll
        for (int i = 0; i < 4; i++) {
            out[pbase + 0*16 + quad*4 + i] = rsum0[i];
            out[pbase + 1*16 + quad*4 + i] = rsum1[i];
        }
    }
}

// ---------------------------------------------------------------------------
extern "C" void kernel_launch(void* const* d_in, const int* in_sizes, int n_in,
                              void* d_out, int out_size, void* d_ws, size_t ws_size,
                              hipStream_t stream) {
    const float* x      = (const float*)d_in[0];
    const float* t      = (const float*)d_in[1];
    const float* alpha  = (const float*)d_in[2];
    const float* tab_s  = (const float*)d_in[3];
    const float* ws_in  = (const float*)d_in[4];
    const float* ws_hid = (const float*)d_in[5];
    const float* ws_out = (const float*)d_in[6];
    const float* tab_d  = (const float*)d_in[7];
    const float* wd_in  = (const float*)d_in[8];
    const float* wd_hid = (const float*)d_in[9];
    const float* wd_out = (const float*)d_in[10];
    const float* w1_in  = (const float*)d_in[11];
    const float* w1_hid = (const float*)d_in[12];
    const float* w1_out = (const float*)d_in[13];
    const float* w2_in  = (const float*)d_in[14];
    const float* w2_hid = (const float*)d_in[15];
    const float* w2_out = (const float*)d_in[16];
    float* out = (float*)d_out;

    char* ws = (char*)d_ws;
    _Float16* Wfrag = (_Float16*)ws;                       // 139264 B
    uint2*    Tc    = (uint2*)(ws + 139264);               // 64 MiB combined table
    uint32_t* EncS  = (uint32_t*)(ws + 139264 + 67108864); // 32 MiB [lvl][pt]
    uint32_t* EncD  = EncS + (size_t)LVLS * NPTS;          // 32 MiB [lvl][pt]
    size_t needed = 139264 + 67108864 + 2ull * 33554432ull;
    if (ws_size < needed) return;

    WPtrs wp;
    wp.p[0] = ws_in;  wp.p[1] = ws_hid; wp.p[2] = ws_out;
    wp.p[3] = wd_in;  wp.p[4] = wd_hid; wp.p[5] = wd_out;
    wp.p[6] = w1_in;  wp.p[7] = w1_hid; wp.p[8] = w1_out;
    wp.p[9] = w2_in;  wp.p[10] = w2_hid;

    k_weights<<<272,   256, 0, stream>>>(wp, Wfrag);
    k_tables <<<32768, 256, 0, stream>>>(tab_s, tab_d, t, Tc);
    k_encode <<<2048,  256, 0, stream>>>(x, Tc, EncS, EncD);
    k_mlp    <<<NPTS/128, 256, 0, stream>>>(EncS, EncD, Wfrag, alpha, w2_out, out);
}

// Round 6
// 619.883 us; speedup vs baseline: 1.1935x; 1.0568x over previous
//
#include <hip/hip_runtime.h>
#include <hip/hip_bf16.h>
#include <stdint.h>

#define LVLS 16
#define TSZ  524288          // hash table size per level (2^19)
#define TMASK 0x7FFFFu
#define NPTS 524288
#define P1 2654435761u
#define P2 805459861u
#define P3 3674653429u

// floor(16 * 1.5^l), hardcoded
__constant__ float RES_TAB[16] = {
    16.f, 24.f, 36.f, 54.f, 81.f, 121.f, 182.f, 273.f,
    410.f, 615.f, 922.f, 1383.f, 2075.f, 3113.f, 4670.f, 7006.f};

using f16x8 = __attribute__((ext_vector_type(8))) _Float16;
using f32x4 = __attribute__((ext_vector_type(4))) float;

union PackF16 { uint32_t u; _Float16 h[2]; };

constexpr int PS = 72;    // LDS row pitch (64 cols + 8 pad)

// ---------------------------------------------------------------------------
// Kernel W: swizzle weights (fp32 [K][N] row-major) into f16 B-fragment layout
// for mfma_f32_16x16x32_f16 (verified r1-r5):
//   dst[((ct*KC+kc)*64+lane)*8+j] = W[kc*32+(lane>>4)*8+j][ct*16+(lane&15)]
// ---------------------------------------------------------------------------
struct WPtrs { const float* p[11]; };

__global__ void k_weights(WPtrs wp, _Float16* __restrict__ dst) {
    int id = blockIdx.x * 256 + threadIdx.x;
    if (id >= 69632) return;
    const int OFF[16] = {0,2048,6144,10240,14336,18432,20480,24576,28672,
                         32768,36864,45056,49152,57344,65536,69632};
    const int KK[15]  = {32,64,64,64,64,32,64,64,64,64,128,64,64,128,64};
    const int NN[15]  = {64,64,64,64,64,64,64,64,64,64,64,64,128,64,64};
    const int PSEL[15]= {0,1,1,1,2,3,4,4,4,5,6,7,8,9,10};
    const int POFF[15]= {0,0,4096,8192,0,0,0,4096,8192,0,0,0,0,0,0};
    int m = 0;
    while (id >= OFF[m+1]) m++;
    int local = id - OFF[m];
    int j    = local & 7;
    int lane = (local >> 3) & 63;
    int blk  = local >> 9;
    int KC   = KK[m] >> 5;
    int ct   = blk / KC;
    int kc   = blk - ct * KC;
    int k    = kc*32 + ((lane>>4)<<3) + j;
    int n    = ct*16 + (lane & 15);
    const float* src = wp.p[PSEL[m]] + POFF[m];
    dst[id] = (_Float16)src[k * NN[m] + n];
}

// ---------------------------------------------------------------------------
// Kernel T: combined f16 table. Tc[l][i] = { static(i), t-blended dynamic }:
//   dynamic = (1-ft)*td[l][i^h0] + ft*td[l][i^h1]  (t-corner hashes baked in)
// ---------------------------------------------------------------------------
__global__ void k_tables(const float* __restrict__ ts, const float* __restrict__ td,
                         const float* __restrict__ tptr, uint2* __restrict__ Tc) {
    int id = blockIdx.x * 256 + threadIdx.x;   // 0 .. LVLS*TSZ-1
    int l = id >> 19, i = id & TMASK;
    float2 sv = ((const float2*)ts)[id];
    float res = RES_TAB[l];
    float tv  = tptr[0];
    float pt  = tv * res;
    float fpt = floorf(pt);
    float ft  = pt - fpt;
    uint32_t ut = (uint32_t)(int)fpt;
    uint32_t h0 = (ut * P3) & TMASK;
    uint32_t h1 = ((ut + 1u) * P3) & TMASK;
    const float2* tdl = (const float2*)td + (size_t)l * TSZ;
    float2 a = tdl[i ^ h0];
    float2 b = tdl[i ^ h1];
    PackF16 o0, o1;
    o0.h[0] = (_Float16)sv.x; o0.h[1] = (_Float16)sv.y;
    o1.h[0] = (_Float16)((1.f - ft) * a.x + ft * b.x);
    o1.h[1] = (_Float16)((1.f - ft) * a.y + ft * b.y);
    Tc[id] = make_uint2(o0.u, o1.u);
}

// ---------------------------------------------------------------------------
// Kernel E: hash-grid encode, XCD-sharded, BALANCED (16 pts/thread uniform).
// Class c (= blockIdx&7, round-robin -> XCD-pinned) runs 3 hard half-units
// (levels 4..15 split into 24 halves) then 1 coarse half-unit (levels 0..3
// split into 8 halves). One 4 MiB level slice live per XCD at a time.
// Batch-4 points: phase 1 issues all 32 gathers (idx regs die at issue),
// phase 2 consumes in order. __launch_bounds__(256,4) allows ~128 VGPRs so
// the compiler can keep all 32 results in flight (r5's 36-VGPR chunking fix).
// ---------------------------------------------------------------------------
__device__ __forceinline__ void enc_batch4(const float* __restrict__ x,
                                           const uint2* __restrict__ tcl, float res,
                                           uint32_t* __restrict__ es,
                                           uint32_t* __restrict__ ed, int pb) {
    float fr[4][3];
    uint2 v[4][8];
    // phase 1: fracs + indices, issue gathers
#pragma unroll
    for (int b = 0; b < 4; b++) {
        int p = pb + b * 65536;
        float px = x[p*3+0]*res, py = x[p*3+1]*res, pz = x[p*3+2]*res;
        float fx = floorf(px), fy = floorf(py), fz = floorf(pz);
        fr[b][0] = px-fx; fr[b][1] = py-fy; fr[b][2] = pz-fz;
        uint32_t ux = (uint32_t)(int)fx, uy = (uint32_t)(int)fy, uz = (uint32_t)(int)fz;
        uint32_t hx[2] = {ux, ux + 1u};
        uint32_t hy[2] = {uy * P1, (uy + 1u) * P1};
        uint32_t hz[2] = {uz * P2, (uz + 1u) * P2};
#pragma unroll
        for (int c = 0; c < 8; c++) {
            uint32_t idx = (hx[c&1] ^ hy[(c>>1)&1] ^ hz[c>>2]) & TMASK;
            v[b][c] = tcl[idx];
        }
    }
    // phase 2: weights + reduce + store, in issue order
#pragma unroll
    for (int b = 0; b < 4; b++) {
        float wxa[2] = {1.f - fr[b][0], fr[b][0]};
        float wya[2] = {1.f - fr[b][1], fr[b][1]};
        float wza[2] = {1.f - fr[b][2], fr[b][2]};
        float sA0 = 0.f, sA1 = 0.f, sD0 = 0.f, sD1 = 0.f;
#pragma unroll
        for (int c = 0; c < 8; c++) {
            float w = wxa[c&1] * wya[(c>>1)&1] * wza[c>>2];
            PackF16 s, d; s.u = v[b][c].x; d.u = v[b][c].y;
            sA0 += w * (float)s.h[0]; sA1 += w * (float)s.h[1];
            sD0 += w * (float)d.h[0]; sD1 += w * (float)d.h[1];
        }
        PackF16 o;
        int p = pb + b * 65536;
        o.h[0] = (_Float16)sA0; o.h[1] = (_Float16)sA1; es[p] = o.u;
        o.h[0] = (_Float16)sD0; o.h[1] = (_Float16)sD1; ed[p] = o.u;
    }
}

__launch_bounds__(256, 4)
__global__ void k_encode(const float* __restrict__ x,
                         const uint2* __restrict__ Tc,
                         uint32_t* __restrict__ EncS, uint32_t* __restrict__ EncD) {
    int tid = threadIdx.x;
    int cls = blockIdx.x & 7;
    int gt  = (blockIdx.x >> 3) * 256 + tid;   // 0..65535 within class
    // 3 hard half-units (levels 4..15)
#pragma unroll
    for (int u3 = 0; u3 < 3; u3++) {
        int u = cls * 3 + u3;
        int l = 4 + (u >> 1);
        int pb = (u & 1) * 262144 + gt;
        enc_batch4(x, Tc + (size_t)l * TSZ, RES_TAB[l],
                   EncS + (size_t)l * NPTS, EncD + (size_t)l * NPTS, pb);
    }
    // 1 coarse half-unit (levels 0..3, cache-resident)
    {
        int l = cls >> 1;
        int pb = (cls & 1) * 262144 + gt;
        enc_batch4(x, Tc + (size_t)l * TSZ, RES_TAB[l],
                   EncS + (size_t)l * NPTS, EncD + (size_t)l * NPTS, pb);
    }
}

// ---------------------------------------------------------------------------
// Kernel M: barrier-free MLP (r5-verified). Wave-private 32-point tiles
// (rt=2, B-frag reg reuse x2); B-fragments from global (L1-resident).
// In-place layers via per-wave in-order DS + lgkmcnt. Two 32x72 f16 buffers
// per wave -> 36.9 KB/block -> 4 blocks/CU.
// Fragment maps: A[m=lane&15][k=quad*8+j], D row=quad*4+i, col=lane&15.
// ---------------------------------------------------------------------------
__device__ __forceinline__ void wait_lds() {
    asm volatile("s_waitcnt lgkmcnt(0)" ::: "memory");
}

template<int KC, bool RELU>
__device__ __forceinline__ void mm2(const f16x8 a[2][4], const f16x8* __restrict__ B,
                                    _Float16* dst, int m, int quad, int lane) {
#pragma unroll
    for (int ct = 0; ct < 4; ct++) {
        f32x4 acc0 = {0.f,0.f,0.f,0.f}, acc1 = {0.f,0.f,0.f,0.f};
#pragma unroll
        for (int kc = 0; kc < KC; kc++) {
            f16x8 b = B[(ct*KC+kc)*64 + lane];
            acc0 = __builtin_amdgcn_mfma_f32_16x16x32_f16(a[0][kc], b, acc0, 0, 0, 0);
            acc1 = __builtin_amdgcn_mfma_f32_16x16x32_f16(a[1][kc], b, acc1, 0, 0, 0);
        }
#pragma unroll
        for (int i = 0; i < 4; i++) {
            float v0 = acc0[i], v1 = acc1[i];
            if (RELU) { v0 = fmaxf(v0, 0.f); v1 = fmaxf(v1, 0.f); }
            dst[(0*16 + quad*4+i)*PS + ct*16 + m] = (_Float16)v0;
            dst[(1*16 + quad*4+i)*PS + ct*16 + m] = (_Float16)v1;
        }
    }
}

// linear-out layer: write D to dst AND keep packed f16 copy (skip connection)
template<int KC>
__device__ __forceinline__ void mm2_keep(const f16x8 a[2][4], const f16x8* __restrict__ B,
                                         _Float16* dst, PackF16 P[2][8],
                                         int m, int quad, int lane) {
#pragma unroll
    for (int ct = 0; ct < 4; ct++) {
        f32x4 acc0 = {0.f,0.f,0.f,0.f}, acc1 = {0.f,0.f,0.f,0.f};
#pragma unroll
        for (int kc = 0; kc < KC; kc++) {
            f16x8 b = B[(ct*KC+kc)*64 + lane];
            acc0 = __builtin_amdgcn_mfma_f32_16x16x32_f16(a[0][kc], b, acc0, 0, 0, 0);
            acc1 = __builtin_amdgcn_mfma_f32_16x16x32_f16(a[1][kc], b, acc1, 0, 0, 0);
        }
#pragma unroll
        for (int ih = 0; ih < 2; ih++) {
            PackF16 p0, p1;
            p0.h[0] = (_Float16)acc0[ih*2+0]; p0.h[1] = (_Float16)acc0[ih*2+1];
            p1.h[0] = (_Float16)acc1[ih*2+0]; p1.h[1] = (_Float16)acc1[ih*2+1];
            P[0][ct*2+ih] = p0; P[1][ct*2+ih] = p1;
            dst[(0*16 + quad*4+ih*2+0)*PS + ct*16 + m] = p0.h[0];
            dst[(0*16 + quad*4+ih*2+1)*PS + ct*16 + m] = p0.h[1];
            dst[(1*16 + quad*4+ih*2+0)*PS + ct*16 + m] = p1.h[0];
            dst[(1*16 + quad*4+ih*2+1)*PS + ct*16 + m] = p1.h[1];
        }
    }
}

template<int KC>
__device__ __forceinline__ void read_a(const _Float16* buf, f16x8 a[2][4], int m, int quad) {
#pragma unroll
    for (int rt = 0; rt < 2; rt++)
#pragma unroll
        for (int kc = 0; kc < KC; kc++)
            a[rt][kc] = *(const f16x8*)(buf + (rt*16 + m)*PS + kc*32 + quad*8);
}

__device__ __forceinline__ void read_a128(const _Float16* Fs, const _Float16* Fd,
                                          f16x8 a[2][4], int m, int quad) {
#pragma unroll
    for (int rt = 0; rt < 2; rt++) {
#pragma unroll
        for (int kc = 0; kc < 2; kc++) {
            a[rt][kc]   = *(const f16x8*)(Fs + (rt*16 + m)*PS + kc*32 + quad*8);
            a[rt][kc+2] = *(const f16x8*)(Fd + (rt*16 + m)*PS + kc*32 + quad*8);
        }
    }
}

__device__ __forceinline__ void load_enc(const uint32_t* __restrict__ Enc,
                                         int pbase, int m, int quad, f16x8 a[2][4]) {
#pragma unroll
    for (int rt = 0; rt < 2; rt++) {
        union { uint32_t u[4]; f16x8 v; } cv;
        int p = pbase + rt*16 + m;
#pragma unroll
        for (int j = 0; j < 4; j++)
            cv.u[j] = Enc[(size_t)(quad*4 + j) * NPTS + p];
        a[rt][0] = cv.v;
    }
}

__launch_bounds__(256, 4)
__global__ void k_mlp(const uint32_t* __restrict__ EncS, const uint32_t* __restrict__ EncD,
                      const _Float16* __restrict__ Wfrag, const float* __restrict__ alphap,
                      const float* __restrict__ w2out, float* __restrict__ out) {
    __shared__ _Float16 FsB[4][32*PS];
    __shared__ _Float16 FdB[4][32*PS];
    int tid  = threadIdx.x;
    int wave = tid >> 6, lane = tid & 63;
    int m = lane & 15, quad = lane >> 4;
    int pbase = blockIdx.x * 128 + wave * 32;
    _Float16* Fs = FsB[wave];
    _Float16* Fd = FdB[wave];
    const f16x8* W8 = (const f16x8*)Wfrag;
    float alpha = alphap[0];

    f16x8 a[2][4];
    PackF16 sP[2][8], dP[2][8];

    // ---- static encoder chain, in-place in Fs ----
    load_enc(EncS, pbase, m, quad, a);
    mm2<1, true>(a, W8 + 0,    Fs, m, quad, lane); wait_lds();
    read_a<2>(Fs, a, m, quad);
    mm2<2, true>(a, W8 + 256,  Fs, m, quad, lane); wait_lds();
    read_a<2>(Fs, a, m, quad);
    mm2<2, true>(a, W8 + 768,  Fs, m, quad, lane); wait_lds();
    read_a<2>(Fs, a, m, quad);
    mm2<2, true>(a, W8 + 1280, Fs, m, quad, lane); wait_lds();
    read_a<2>(Fs, a, m, quad);
    mm2_keep<2>(a, W8 + 1792, Fs, sP, m, quad, lane);
    // ---- dynamic encoder chain, in-place in Fd ----
    load_enc(EncD, pbase, m, quad, a);
    mm2<1, true>(a, W8 + 2304, Fd, m, quad, lane); wait_lds();
    read_a<2>(Fd, a, m, quad);
    mm2<2, true>(a, W8 + 2560, Fd, m, quad, lane); wait_lds();
    read_a<2>(Fd, a, m, quad);
    mm2<2, true>(a, W8 + 3072, Fd, m, quad, lane); wait_lds();
    read_a<2>(Fd, a, m, quad);
    mm2<2, true>(a, W8 + 3584, Fd, m, quad, lane); wait_lds();
    read_a<2>(Fd, a, m, quad);
    mm2_keep<2>(a, W8 + 4096, Fd, dP, m, quad, lane); wait_lds();
    // ---- mlp1: 128->64 relu (reads Fs|Fd, writes Fs), 64->64 relu ----
    read_a128(Fs, Fd, a, m, quad);
    mm2<4, true>(a, W8 + 4608, Fs, m, quad, lane); wait_lds();
    read_a<2>(Fs, a, m, quad);
    mm2<2, true>(a, W8 + 5632, Fs, m, quad, lane); wait_lds();
    read_a<2>(Fs, a, m, quad);
    // ---- out1 (64->128) fused with skip blend -> Fs (cols 0..63) | Fd ----
#pragma unroll
    for (int ct = 0; ct < 8; ct++) {
        f32x4 acc0 = {0.f,0.f,0.f,0.f}, acc1 = {0.f,0.f,0.f,0.f};
#pragma unroll
        for (int kc = 0; kc < 2; kc++) {
            f16x8 b = W8[6144 + (ct*2+kc)*64 + lane];
            acc0 = __builtin_amdgcn_mfma_f32_16x16x32_f16(a[0][kc], b, acc0, 0, 0, 0);
            acc1 = __builtin_amdgcn_mfma_f32_16x16x32_f16(a[1][kc], b, acc1, 0, 0, 0);
        }
        _Float16* tgt = (ct < 4) ? Fs : Fd;
        int col = (ct & 3) * 16 + m;
#pragma unroll
        for (int i = 0; i < 4; i++) {
            float f0 = (ct < 4) ? (float)sP[0][ct*2 + (i>>1)].h[i&1]
                                : (float)dP[0][(ct-4)*2 + (i>>1)].h[i&1];
            float f1 = (ct < 4) ? (float)sP[1][ct*2 + (i>>1)].h[i&1]
                                : (float)dP[1][(ct-4)*2 + (i>>1)].h[i&1];
            tgt[(0*16 + quad*4+i)*PS + col] = (_Float16)(alpha*acc0[i] + (1.f-alpha)*f0);
            tgt[(1*16 + quad*4+i)*PS + col] = (_Float16)(alpha*acc1[i] + (1.f-alpha)*f1);
        }
    }
    wait_lds();
    // ---- mlp2: 128->64 relu (reads Fs|Fd, writes Fs), 64->64 relu, dot ----
    read_a128(Fs, Fd, a, m, quad);
    mm2<4, true>(a, W8 + 7168, Fs, m, quad, lane); wait_lds();
    read_a<2>(Fs, a, m, quad);
    float rsum0[4] = {0.f,0.f,0.f,0.f}, rsum1[4] = {0.f,0.f,0.f,0.f};
#pragma unroll
    for (int ct = 0; ct < 4; ct++) {
        f32x4 acc0 = {0.f,0.f,0.f,0.f}, acc1 = {0.f,0.f,0.f,0.f};
#pragma unroll
        for (int kc = 0; kc < 2; kc++) {
            f16x8 b = W8[8192 + (ct*2+kc)*64 + lane];
            acc0 = __builtin_amdgcn_mfma_f32_16x16x32_f16(a[0][kc], b, acc0, 0, 0, 0);
            acc1 = __builtin_amdgcn_mfma_f32_16x16x32_f16(a[1][kc], b, acc1, 0, 0, 0);
        }
        float wv = w2out[ct*16 + m];
#pragma unroll
        for (int i = 0; i < 4; i++) {
            rsum0[i] += fmaxf(acc0[i], 0.f) * wv;
            rsum1[i] += fmaxf(acc1[i], 0.f) * wv;
        }
    }
#pragma unroll
    for (int off = 1; off < 16; off <<= 1) {
#pragma unroll
        for (int i = 0; i < 4; i++) {
            rsum0[i] += __shfl_xor(rsum0[i], off, 64);
            rsum1[i] += __shfl_xor(rsum1[i], off, 64);
        }
    }
    if (m == 0) {
#pragma unroll
        for (int i = 0; i < 4; i++) {
            out[pbase + 0*16 + quad*4 + i] = rsum0[i];
            out[pbase + 1*16 + quad*4 + i] = rsum1[i];
        }
    }
}

// ---------------------------------------------------------------------------
extern "C" void kernel_launch(void* const* d_in, const int* in_sizes, int n_in,
                              void* d_out, int out_size, void* d_ws, size_t ws_size,
                              hipStream_t stream) {
    const float* x      = (const float*)d_in[0];
    const float* t      = (const float*)d_in[1];
    const float* alpha  = (const float*)d_in[2];
    const float* tab_s  = (const float*)d_in[3];
    const float* ws_in  = (const float*)d_in[4];
    const float* ws_hid = (const float*)d_in[5];
    const float* ws_out = (const float*)d_in[6];
    const float* tab_d  = (const float*)d_in[7];
    const float* wd_in  = (const float*)d_in[8];
    const float* wd_hid = (const float*)d_in[9];
    const float* wd_out = (const float*)d_in[10];
    const float* w1_in  = (const float*)d_in[11];
    const float* w1_hid = (const float*)d_in[12];
    const float* w1_out = (const float*)d_in[13];
    const float* w2_in  = (const float*)d_in[14];
    const float* w2_hid = (const float*)d_in[15];
    const float* w2_out = (const float*)d_in[16];
    float* out = (float*)d_out;

    char* ws = (char*)d_ws;
    _Float16* Wfrag = (_Float16*)ws;                       // 139264 B
    uint2*    Tc    = (uint2*)(ws + 139264);               // 64 MiB combined table
    uint32_t* EncS  = (uint32_t*)(ws + 139264 + 67108864); // 32 MiB [lvl][pt]
    uint32_t* EncD  = EncS + (size_t)LVLS * NPTS;          // 32 MiB [lvl][pt]
    size_t needed = 139264 + 67108864 + 2ull * 33554432ull;
    if (ws_size < needed) return;

    WPtrs wp;
    wp.p[0] = ws_in;  wp.p[1] = ws_hid; wp.p[2] = ws_out;
    wp.p[3] = wd_in;  wp.p[4] = wd_hid; wp.p[5] = wd_out;
    wp.p[6] = w1_in;  wp.p[7] = w1_hid; wp.p[8] = w1_out;
    wp.p[9] = w2_in;  wp.p[10] = w2_hid;

    k_weights<<<272,   256, 0, stream>>>(wp, Wfrag);
    k_tables <<<32768, 256, 0, stream>>>(tab_s, tab_d, t, Tc);
    k_encode <<<2048,  256, 0, stream>>>(x, Tc, EncS, EncD);
    k_mlp    <<<NPTS/128, 256, 0, stream>>>(EncS, EncD, Wfrag, alpha, w2_out, out);
}

// Round 7
// 597.329 us; speedup vs baseline: 1.2385x; 1.0378x over previous
//
#include <hip/hip_runtime.h>
#include <hip/hip_bf16.h>
#include <stdint.h>

#define LVLS 16
#define TSZ  524288          // hash table size per level (2^19)
#define TMASK 0x7FFFFu
#define NPTS 524288
#define P1 2654435761u
#define P2 805459861u
#define P3 3674653429u

// floor(16 * 1.5^l), hardcoded
__constant__ float RES_TAB[16] = {
    16.f, 24.f, 36.f, 54.f, 81.f, 121.f, 182.f, 273.f,
    410.f, 615.f, 922.f, 1383.f, 2075.f, 3113.f, 4670.f, 7006.f};

using f16x8 = __attribute__((ext_vector_type(8))) _Float16;
using f32x4 = __attribute__((ext_vector_type(4))) float;

union PackF16 { uint32_t u; _Float16 h[2]; };

constexpr int PS = 72;    // LDS row pitch (64 cols + 8 pad)

struct WPtrs { const float* p[11]; };

// ---------------------------------------------------------------------------
// Kernel B: XCD-pinned table build + weight swizzle (merged).
// Class c = blockIdx&7 (round-robin -> XCD c). Build order within class:
//   j in [0,1024)     : coarse level c>>1, half c&1       (cheap, first)
//   j in [1024,3072)  : SHARED level 12+(c>>1), full      (dup per class pair)
//   j in [3072,5120)  : EXCLUSIVE level 4+c, full         (LAST -> hottest L2)
// Encode (next kernel, same XCD classes) reads the exclusive slice first,
// straight out of the XCD's L2.
// Tc[l][i] = { static(i) , (1-ft)*td[l][i^h0] + ft*td[l][i^h1] }  (t baked in)
// Tail blocks (>= 40960) do the weight-fragment swizzle (verified r1-r6):
//   dst[((ct*KC+kc)*64+lane)*8+j] = W[kc*32+(lane>>4)*8+j][ct*16+(lane&15)]
// ---------------------------------------------------------------------------
__global__ void k_build(const float* __restrict__ ts, const float* __restrict__ td,
                        const float* __restrict__ tptr, uint2* __restrict__ Tc,
                        WPtrs wp, _Float16* __restrict__ wdst) {
    int B = blockIdx.x;
    int tid = threadIdx.x;
    if (B < 40960) {
        int c = B & 7, j = B >> 3;
        int l, i;
        if (j < 1024) {
            l = c >> 1;
            i = (c & 1) * 262144 + j * 256 + tid;
        } else if (j < 3072) {
            l = 12 + (c >> 1);
            i = (j - 1024) * 256 + tid;
        } else {
            l = 4 + c;
            i = (j - 3072) * 256 + tid;
        }
        int id = l * TSZ + i;
        float2 sv = ((const float2*)ts)[id];
        float res = RES_TAB[l];
        float tv  = tptr[0];
        float pt  = tv * res;
        float fpt = floorf(pt);
        float ft  = pt - fpt;
        uint32_t ut = (uint32_t)(int)fpt;
        uint32_t h0 = (ut * P3) & TMASK;
        uint32_t h1 = ((ut + 1u) * P3) & TMASK;
        const float2* tdl = (const float2*)td + (size_t)l * TSZ;
        float2 a = tdl[i ^ h0];
        float2 b = tdl[i ^ h1];
        PackF16 o0, o1;
        o0.h[0] = (_Float16)sv.x; o0.h[1] = (_Float16)sv.y;
        o1.h[0] = (_Float16)((1.f - ft) * a.x + ft * b.x);
        o1.h[1] = (_Float16)((1.f - ft) * a.y + ft * b.y);
        Tc[id] = make_uint2(o0.u, o1.u);
    } else {
        int id = (B - 40960) * 256 + tid;
        if (id >= 69632) return;
        const int OFF[16] = {0,2048,6144,10240,14336,18432,20480,24576,28672,
                             32768,36864,45056,49152,57344,65536,69632};
        const int KK[15]  = {32,64,64,64,64,32,64,64,64,64,128,64,64,128,64};
        const int NN[15]  = {64,64,64,64,64,64,64,64,64,64,64,64,128,64,64};
        const int PSEL[15]= {0,1,1,1,2,3,4,4,4,5,6,7,8,9,10};
        const int POFF[15]= {0,0,4096,8192,0,0,0,4096,8192,0,0,0,0,0,0};
        int m = 0;
        while (id >= OFF[m+1]) m++;
        int local = id - OFF[m];
        int jj   = local & 7;
        int lane = (local >> 3) & 63;
        int blk  = local >> 9;
        int KC   = KK[m] >> 5;
        int ct   = blk / KC;
        int kc   = blk - ct * KC;
        int k    = kc*32 + ((lane>>4)<<3) + jj;
        int n    = ct*16 + (lane & 15);
        const float* src = wp.p[PSEL[m]] + POFF[m];
        wdst[id] = (_Float16)src[k * NN[m] + n];
    }
}

// ---------------------------------------------------------------------------
// Kernel E: hash-grid encode, XCD-sharded, balanced 1.5 hard levels/class,
// L2-hot handoff from k_build. Class c order:
//   pass 0: EXCLUSIVE level 4+c, all 512K points   (slice hot in this XCD L2)
//   pass 1: SHARED level 12+(c>>1), half c&1       (256K points)
//   pass 2: coarse level c>>1, half c&1            (256K points, cache-light)
// Inner loop = r2's empirically-best shape: 1 point, 8 x 8B gathers.
// ---------------------------------------------------------------------------
__device__ __forceinline__ void enc_point(const float* __restrict__ x,
                                          const uint2* __restrict__ tcl, float res,
                                          uint32_t* __restrict__ es,
                                          uint32_t* __restrict__ ed, int p) {
    float px = x[p*3+0]*res, py = x[p*3+1]*res, pz = x[p*3+2]*res;
    float fx = floorf(px), fy = floorf(py), fz = floorf(pz);
    float wx = px-fx, wy = py-fy, wz = pz-fz;
    uint32_t ux = (uint32_t)(int)fx, uy = (uint32_t)(int)fy, uz = (uint32_t)(int)fz;
    uint32_t hx[2] = {ux, ux + 1u};
    uint32_t hy[2] = {uy * P1, (uy + 1u) * P1};
    uint32_t hz[2] = {uz * P2, (uz + 1u) * P2};
    uint2 v[8];
#pragma unroll
    for (int c = 0; c < 8; c++) {
        uint32_t idx = (hx[c&1] ^ hy[(c>>1)&1] ^ hz[c>>2]) & TMASK;
        v[c] = tcl[idx];
    }
    float wxa[2] = {1.f-wx, wx}, wya[2] = {1.f-wy, wy}, wza[2] = {1.f-wz, wz};
    float sA0 = 0.f, sA1 = 0.f, sD0 = 0.f, sD1 = 0.f;
#pragma unroll
    for (int c = 0; c < 8; c++) {
        float w = wxa[c&1] * wya[(c>>1)&1] * wza[c>>2];
        PackF16 s, d; s.u = v[c].x; d.u = v[c].y;
        sA0 += w * (float)s.h[0]; sA1 += w * (float)s.h[1];
        sD0 += w * (float)d.h[0]; sD1 += w * (float)d.h[1];
    }
    PackF16 o;
    o.h[0] = (_Float16)sA0; o.h[1] = (_Float16)sA1; es[p] = o.u;
    o.h[0] = (_Float16)sD0; o.h[1] = (_Float16)sD1; ed[p] = o.u;
}

__launch_bounds__(256)
__global__ void k_encode(const float* __restrict__ x,
                         const uint2* __restrict__ Tc,
                         uint32_t* __restrict__ EncS, uint32_t* __restrict__ EncD) {
    int tid = threadIdx.x;
    int c   = blockIdx.x & 7;
    int gt  = (blockIdx.x >> 3) * 256 + tid;   // 0..65535 within class
    // pass 0: exclusive hard level (hot from k_build)
    {
        int l = 4 + c;
        const uint2* tcl = Tc + (size_t)l * TSZ;
        uint32_t* es = EncS + (size_t)l * NPTS;
        uint32_t* ed = EncD + (size_t)l * NPTS;
        float res = RES_TAB[l];
        for (int q = 0; q < 8; q++)
            enc_point(x, tcl, res, es, ed, gt + q * 65536);
    }
    // pass 1: shared hard level, half point-set
    {
        int l = 12 + (c >> 1);
        const uint2* tcl = Tc + (size_t)l * TSZ;
        uint32_t* es = EncS + (size_t)l * NPTS;
        uint32_t* ed = EncD + (size_t)l * NPTS;
        float res = RES_TAB[l];
        int pb = (c & 1) * 262144 + gt;
        for (int q = 0; q < 4; q++)
            enc_point(x, tcl, res, es, ed, pb + q * 65536);
    }
    // pass 2: coarse level, half point-set (cache-light: high per-line reuse)
    {
        int l = c >> 1;
        const uint2* tcl = Tc + (size_t)l * TSZ;
        uint32_t* es = EncS + (size_t)l * NPTS;
        uint32_t* ed = EncD + (size_t)l * NPTS;
        float res = RES_TAB[l];
        int pb = (c & 1) * 262144 + gt;
        for (int q = 0; q < 4; q++)
            enc_point(x, tcl, res, es, ed, pb + q * 65536);
    }
}

// ---------------------------------------------------------------------------
// Kernel M: barrier-free MLP (r5/r6-verified, unchanged). Wave-private
// 32-point tiles (rt=2, B-frag reg reuse x2); B-fragments from global
// (L1-resident). In-place layers via per-wave in-order DS + lgkmcnt.
// Two 32x72 f16 buffers per wave -> 36.9 KB/block -> 4 blocks/CU.
// Fragment maps: A[m=lane&15][k=quad*8+j], D row=quad*4+i, col=lane&15.
// ---------------------------------------------------------------------------
__device__ __forceinline__ void wait_lds() {
    asm volatile("s_waitcnt lgkmcnt(0)" ::: "memory");
}

template<int KC, bool RELU>
__device__ __forceinline__ void mm2(const f16x8 a[2][4], const f16x8* __restrict__ B,
                                    _Float16* dst, int m, int quad, int lane) {
#pragma unroll
    for (int ct = 0; ct < 4; ct++) {
        f32x4 acc0 = {0.f,0.f,0.f,0.f}, acc1 = {0.f,0.f,0.f,0.f};
#pragma unroll
        for (int kc = 0; kc < KC; kc++) {
            f16x8 b = B[(ct*KC+kc)*64 + lane];
            acc0 = __builtin_amdgcn_mfma_f32_16x16x32_f16(a[0][kc], b, acc0, 0, 0, 0);
            acc1 = __builtin_amdgcn_mfma_f32_16x16x32_f16(a[1][kc], b, acc1, 0, 0, 0);
        }
#pragma unroll
        for (int i = 0; i < 4; i++) {
            float v0 = acc0[i], v1 = acc1[i];
            if (RELU) { v0 = fmaxf(v0, 0.f); v1 = fmaxf(v1, 0.f); }
            dst[(0*16 + quad*4+i)*PS + ct*16 + m] = (_Float16)v0;
            dst[(1*16 + quad*4+i)*PS + ct*16 + m] = (_Float16)v1;
        }
    }
}

template<int KC>
__device__ __forceinline__ void mm2_keep(const f16x8 a[2][4], const f16x8* __restrict__ B,
                                         _Float16* dst, PackF16 P[2][8],
                                         int m, int quad, int lane) {
#pragma unroll
    for (int ct = 0; ct < 4; ct++) {
        f32x4 acc0 = {0.f,0.f,0.f,0.f}, acc1 = {0.f,0.f,0.f,0.f};
#pragma unroll
        for (int kc = 0; kc < KC; kc++) {
            f16x8 b = B[(ct*KC+kc)*64 + lane];
            acc0 = __builtin_amdgcn_mfma_f32_16x16x32_f16(a[0][kc], b, acc0, 0, 0, 0);
            acc1 = __builtin_amdgcn_mfma_f32_16x16x32_f16(a[1][kc], b, acc1, 0, 0, 0);
        }
#pragma unroll
        for (int ih = 0; ih < 2; ih++) {
            PackF16 p0, p1;
            p0.h[0] = (_Float16)acc0[ih*2+0]; p0.h[1] = (_Float16)acc0[ih*2+1];
            p1.h[0] = (_Float16)acc1[ih*2+0]; p1.h[1] = (_Float16)acc1[ih*2+1];
            P[0][ct*2+ih] = p0; P[1][ct*2+ih] = p1;
            dst[(0*16 + quad*4+ih*2+0)*PS + ct*16 + m] = p0.h[0];
            dst[(0*16 + quad*4+ih*2+1)*PS + ct*16 + m] = p0.h[1];
            dst[(1*16 + quad*4+ih*2+0)*PS + ct*16 + m] = p1.h[0];
            dst[(1*16 + quad*4+ih*2+1)*PS + ct*16 + m] = p1.h[1];
        }
    }
}

template<int KC>
__device__ __forceinline__ void read_a(const _Float16* buf, f16x8 a[2][4], int m, int quad) {
#pragma unroll
    for (int rt = 0; rt < 2; rt++)
#pragma unroll
        for (int kc = 0; kc < KC; kc++)
            a[rt][kc] = *(const f16x8*)(buf + (rt*16 + m)*PS + kc*32 + quad*8);
}

__device__ __forceinline__ void read_a128(const _Float16* Fs, const _Float16* Fd,
                                          f16x8 a[2][4], int m, int quad) {
#pragma unroll
    for (int rt = 0; rt < 2; rt++) {
#pragma unroll
        for (int kc = 0; kc < 2; kc++) {
            a[rt][kc]   = *(const f16x8*)(Fs + (rt*16 + m)*PS + kc*32 + quad*8);
            a[rt][kc+2] = *(const f16x8*)(Fd + (rt*16 + m)*PS + kc*32 + quad*8);
        }
    }
}

__device__ __forceinline__ void load_enc(const uint32_t* __restrict__ Enc,
                                         int pbase, int m, int quad, f16x8 a[2][4]) {
#pragma unroll
    for (int rt = 0; rt < 2; rt++) {
        union { uint32_t u[4]; f16x8 v; } cv;
        int p = pbase + rt*16 + m;
#pragma unroll
        for (int j = 0; j < 4; j++)
            cv.u[j] = Enc[(size_t)(quad*4 + j) * NPTS + p];
        a[rt][0] = cv.v;
    }
}

__launch_bounds__(256, 4)
__global__ void k_mlp(const uint32_t* __restrict__ EncS, const uint32_t* __restrict__ EncD,
                      const _Float16* __restrict__ Wfrag, const float* __restrict__ alphap,
                      const float* __restrict__ w2out, float* __restrict__ out) {
    __shared__ _Float16 FsB[4][32*PS];
    __shared__ _Float16 FdB[4][32*PS];
    int tid  = threadIdx.x;
    int wave = tid >> 6, lane = tid & 63;
    int m = lane & 15, quad = lane >> 4;
    int pbase = blockIdx.x * 128 + wave * 32;
    _Float16* Fs = FsB[wave];
    _Float16* Fd = FdB[wave];
    const f16x8* W8 = (const f16x8*)Wfrag;
    float alpha = alphap[0];

    f16x8 a[2][4];
    PackF16 sP[2][8], dP[2][8];

    // ---- static encoder chain, in-place in Fs ----
    load_enc(EncS, pbase, m, quad, a);
    mm2<1, true>(a, W8 + 0,    Fs, m, quad, lane); wait_lds();
    read_a<2>(Fs, a, m, quad);
    mm2<2, true>(a, W8 + 256,  Fs, m, quad, lane); wait_lds();
    read_a<2>(Fs, a, m, quad);
    mm2<2, true>(a, W8 + 768,  Fs, m, quad, lane); wait_lds();
    read_a<2>(Fs, a, m, quad);
    mm2<2, true>(a, W8 + 1280, Fs, m, quad, lane); wait_lds();
    read_a<2>(Fs, a, m, quad);
    mm2_keep<2>(a, W8 + 1792, Fs, sP, m, quad, lane);
    // ---- dynamic encoder chain, in-place in Fd ----
    load_enc(EncD, pbase, m, quad, a);
    mm2<1, true>(a, W8 + 2304, Fd, m, quad, lane); wait_lds();
    read_a<2>(Fd, a, m, quad);
    mm2<2, true>(a, W8 + 2560, Fd, m, quad, lane); wait_lds();
    read_a<2>(Fd, a, m, quad);
    mm2<2, true>(a, W8 + 3072, Fd, m, quad, lane); wait_lds();
    read_a<2>(Fd, a, m, quad);
    mm2<2, true>(a, W8 + 3584, Fd, m, quad, lane); wait_lds();
    read_a<2>(Fd, a, m, quad);
    mm2_keep<2>(a, W8 + 4096, Fd, dP, m, quad, lane); wait_lds();
    // ---- mlp1: 128->64 relu (reads Fs|Fd, writes Fs), 64->64 relu ----
    read_a128(Fs, Fd, a, m, quad);
    mm2<4, true>(a, W8 + 4608, Fs, m, quad, lane); wait_lds();
    read_a<2>(Fs, a, m, quad);
    mm2<2, true>(a, W8 + 5632, Fs, m, quad, lane); wait_lds();
    read_a<2>(Fs, a, m, quad);
    // ---- out1 (64->128) fused with skip blend -> Fs (cols 0..63) | Fd ----
#pragma unroll
    for (int ct = 0; ct < 8; ct++) {
        f32x4 acc0 = {0.f,0.f,0.f,0.f}, acc1 = {0.f,0.f,0.f,0.f};
#pragma unroll
        for (int kc = 0; kc < 2; kc++) {
            f16x8 b = W8[6144 + (ct*2+kc)*64 + lane];
            acc0 = __builtin_amdgcn_mfma_f32_16x16x32_f16(a[0][kc], b, acc0, 0, 0, 0);
            acc1 = __builtin_amdgcn_mfma_f32_16x16x32_f16(a[1][kc], b, acc1, 0, 0, 0);
        }
        _Float16* tgt = (ct < 4) ? Fs : Fd;
        int col = (ct & 3) * 16 + m;
#pragma unroll
        for (int i = 0; i < 4; i++) {
            float f0 = (ct < 4) ? (float)sP[0][ct*2 + (i>>1)].h[i&1]
                                : (float)dP[0][(ct-4)*2 + (i>>1)].h[i&1];
            float f1 = (ct < 4) ? (float)sP[1][ct*2 + (i>>1)].h[i&1]
                                : (float)dP[1][(ct-4)*2 + (i>>1)].h[i&1];
            tgt[(0*16 + quad*4+i)*PS + col] = (_Float16)(alpha*acc0[i] + (1.f-alpha)*f0);
            tgt[(1*16 + quad*4+i)*PS + col] = (_Float16)(alpha*acc1[i] + (1.f-alpha)*f1);
        }
    }
    wait_lds();
    // ---- mlp2: 128->64 relu (reads Fs|Fd, writes Fs), 64->64 relu, dot ----
    read_a128(Fs, Fd, a, m, quad);
    mm2<4, true>(a, W8 + 7168, Fs, m, quad, lane); wait_lds();
    read_a<2>(Fs, a, m, quad);
    float rsum0[4] = {0.f,0.f,0.f,0.f}, rsum1[4] = {0.f,0.f,0.f,0.f};
#pragma unroll
    for (int ct = 0; ct < 4; ct++) {
        f32x4 acc0 = {0.f,0.f,0.f,0.f}, acc1 = {0.f,0.f,0.f,0.f};
#pragma unroll
        for (int kc = 0; kc < 2; kc++) {
            f16x8 b = W8[8192 + (ct*2+kc)*64 + lane];
            acc0 = __builtin_amdgcn_mfma_f32_16x16x32_f16(a[0][kc], b, acc0, 0, 0, 0);
            acc1 = __builtin_amdgcn_mfma_f32_16x16x32_f16(a[1][kc], b, acc1, 0, 0, 0);
        }
        float wv = w2out[ct*16 + m];
#pragma unroll
        for (int i = 0; i < 4; i++) {
            rsum0[i] += fmaxf(acc0[i], 0.f) * wv;
            rsum1[i] += fmaxf(acc1[i], 0.f) * wv;
        }
    }
#pragma unroll
    for (int off = 1; off < 16; off <<= 1) {
#pragma unroll
        for (int i = 0; i < 4; i++) {
            rsum0[i] += __shfl_xor(rsum0[i], off, 64);
            rsum1[i] += __shfl_xor(rsum1[i], off, 64);
        }
    }
    if (m == 0) {
#pragma unroll
        for (int i = 0; i < 4; i++) {
            out[pbase + 0*16 + quad*4 + i] = rsum0[i];
            out[pbase + 1*16 + quad*4 + i] = rsum1[i];
        }
    }
}

// ---------------------------------------------------------------------------
extern "C" void kernel_launch(void* const* d_in, const int* in_sizes, int n_in,
                              void* d_out, int out_size, void* d_ws, size_t ws_size,
                              hipStream_t stream) {
    const float* x      = (const float*)d_in[0];
    const float* t      = (const float*)d_in[1];
    const float* alpha  = (const float*)d_in[2];
    const float* tab_s  = (const float*)d_in[3];
    const float* ws_in  = (const float*)d_in[4];
    const float* ws_hid = (const float*)d_in[5];
    const float* ws_out = (const float*)d_in[6];
    const float* tab_d  = (const float*)d_in[7];
    const float* wd_in  = (const float*)d_in[8];
    const float* wd_hid = (const float*)d_in[9];
    const float* wd_out = (const float*)d_in[10];
    const float* w1_in  = (const float*)d_in[11];
    const float* w1_hid = (const float*)d_in[12];
    const float* w1_out = (const float*)d_in[13];
    const float* w2_in  = (const float*)d_in[14];
    const float* w2_hid = (const float*)d_in[15];
    const float* w2_out = (const float*)d_in[16];
    float* out = (float*)d_out;

    char* ws = (char*)d_ws;
    _Float16* Wfrag = (_Float16*)ws;                       // 139264 B
    uint2*    Tc    = (uint2*)(ws + 139264);               // 64 MiB combined table
    uint32_t* EncS  = (uint32_t*)(ws + 139264 + 67108864); // 32 MiB [lvl][pt]
    uint32_t* EncD  = EncS + (size_t)LVLS * NPTS;          // 32 MiB [lvl][pt]
    size_t needed = 139264 + 67108864 + 2ull * 33554432ull;
    if (ws_size < needed) return;

    WPtrs wp;
    wp.p[0] = ws_in;  wp.p[1] = ws_hid; wp.p[2] = ws_out;
    wp.p[3] = wd_in;  wp.p[4] = wd_hid; wp.p[5] = wd_out;
    wp.p[6] = w1_in;  wp.p[7] = w1_hid; wp.p[8] = w1_out;
    wp.p[9] = w2_in;  wp.p[10] = w2_hid;

    k_build  <<<41232, 256, 0, stream>>>(tab_s, tab_d, t, Tc, wp, Wfrag);
    k_encode <<<2048,  256, 0, stream>>>(x, Tc, EncS, EncD);
    k_mlp    <<<NPTS/128, 256, 0, stream>>>(EncS, EncD, Wfrag, alpha, w2_out, out);
}